// Round 4
// baseline (132.851 us; speedup 1.0000x reference)
//
#include <hip/hip_runtime.h>
#include <math.h>

// B=1, C=256, N=16^3=4096 tokens, 16 groups, 4 heads, d=64.
#define N_TOK 4096
#define C_CH  256

typedef short bf16x8 __attribute__((ext_vector_type(8)));
typedef float f32x4  __attribute__((ext_vector_type(4)));
typedef unsigned short u16;

__device__ __forceinline__ u16 f2bf(float f) {
    union { float f; unsigned u; } v; v.f = f;
    unsigned r = v.u + 0x7FFF + ((v.u >> 16) & 1);   // RNE
    return (u16)(r >> 16);
}
// pack two floats to bf16 pair (truncation) in one v_perm_b32
__device__ __forceinline__ unsigned packtr(float a, float b) {
    union { float f; unsigned u; } ua, ub; ua.f = a; ub.f = b;
    return __builtin_amdgcn_perm(ub.u, ua.u, 0x07060302u);  // lo=hi16(a), hi=hi16(b)
}

// ---------------- prep: weight cvt (blocks 0..1023) + GN partial sums (1024..1279)
// W_q rows pre-scaled by 0.125*log2(e) so softmax can use exp2 directly.
__global__ __launch_bounds__(256) void prep(const float* __restrict__ wqkv,
                                            const float* __restrict__ wproj,
                                            const float* __restrict__ x,
                                            u16* __restrict__ wq, u16* __restrict__ wp,
                                            float2* __restrict__ part) {
    const int b = blockIdx.x, tid = threadIdx.x;
    __shared__ float rs[4], rss[4];
    if (b < 1024) {
        int i = b * 256 + tid;
        if (i < 196608) {
            int row = i >> 8;
            float s = ((row % 192) < 64) ? 0.18033688f : 1.0f;   // 0.125*log2e
            wq[i] = f2bf(wqkv[i] * s);
        } else {
            wp[i - 196608] = f2bf(wproj[i - 196608]);
        }
    } else {
        const int bb = b - 1024;
        const int lane = tid & 63, wave = tid >> 6;
        const float4* xp = (const float4*)x + bb * 1024;
        float s = 0.f, ss = 0.f;
#pragma unroll
        for (int k = 0; k < 4; ++k) {
            float4 v = xp[tid + k * 256];
            s  += v.x + v.y + v.z + v.w;
            ss += v.x * v.x + v.y * v.y + v.z * v.z + v.w * v.w;
        }
#pragma unroll
        for (int off = 1; off < 64; off <<= 1) {
            s  += __shfl_xor(s, off, 64);
            ss += __shfl_xor(ss, off, 64);
        }
        if (lane == 0) { rs[wave] = s; rss[wave] = ss; }
        __syncthreads();
        if (tid == 0) part[bb] = make_float2(rs[0]+rs[1]+rs[2]+rs[3], rss[0]+rss[1]+rss[2]+rss[3]);
    }
}

// ---------------- normalize + transpose -> xt[4096][256] bf16 (stats finalized in-kernel)
__global__ __launch_bounds__(256) void norm_t(const float* __restrict__ x,
                                              const float2* __restrict__ part,
                                              const float* __restrict__ gamma,
                                              const float* __restrict__ beta,
                                              u16* __restrict__ xt) {
    const int tb = blockIdx.x * 64, cb = blockIdx.y * 64;
    const int tid = threadIdx.x;
    __shared__ float sst[8];           // mu,rstd for the 4 groups this block touches
    __shared__ float T[64][65];
    if (tid < 64) {
        float2 p = part[(blockIdx.y * 4 + (tid >> 4)) * 16 + (tid & 15)];
        float s = p.x, ss = p.y;
#pragma unroll
        for (int off = 1; off < 16; off <<= 1) {
            s += __shfl_xor(s, off, 64); ss += __shfl_xor(ss, off, 64);
        }
        if ((tid & 15) == 0) {
            float mu = s / 65536.f;
            float var = ss / 65536.f - mu * mu;
            sst[(tid >> 4) * 2] = mu;
            sst[(tid >> 4) * 2 + 1] = rsqrtf(var + 1e-5f);
        }
    }
    __syncthreads();
#pragma unroll
    for (int it = 0; it < 16; ++it) {
        int idx = tid + it * 256;
        int c = idx >> 6, t = idx & 63;
        int cg = cb + c, gl = c >> 4;
        T[c][t] = (x[cg * N_TOK + tb + t] - sst[gl * 2]) * sst[gl * 2 + 1] * gamma[cg] + beta[cg];
    }
    __syncthreads();
#pragma unroll
    for (int it = 0; it < 16; ++it) {
        int idx = tid + it * 256;
        int t = idx >> 6, c = idx & 63;
        xt[(tb + t) * C_CH + cb + c] = f2bf(T[c][t]);
    }
}

// ---------------- QKV GEMM (bf16 W), routes to QT/KT (token-major) + Vc -----
__global__ __launch_bounds__(256) void qkv_gemm(const u16* __restrict__ wq,
                                                const u16* __restrict__ xt,
                                                u16* __restrict__ QT,
                                                u16* __restrict__ KTm,
                                                u16* __restrict__ Vc) {
    const int nb = blockIdx.x * 64;
    const int mo = blockIdx.y * 64 + (threadIdx.x >> 6) * 16;
    const int lane = threadIdx.x & 63;
    const int quad = lane >> 4, low = lane & 15;

    f32x4 acc[4] = {f32x4{0,0,0,0}, f32x4{0,0,0,0}, f32x4{0,0,0,0}, f32x4{0,0,0,0}};
#pragma unroll
    for (int kc = 0; kc < 8; ++kc) {
        bf16x8 af = *(const bf16x8*)(wq + (mo + low) * 256 + kc * 32 + quad * 8);
#pragma unroll
        for (int nt = 0; nt < 4; ++nt) {
            bf16x8 bf_ = *(const bf16x8*)(xt + (nb + nt * 16 + low) * 256 + kc * 32 + quad * 8);
            acc[nt] = __builtin_amdgcn_mfma_f32_16x16x32_bf16(af, bf_, acc[nt], 0, 0, 0);
        }
    }
#pragma unroll
    for (int r = 0; r < 4; ++r) {
        int o = mo + quad * 4 + r;
        int head = o / 192, rem = o % 192, c = rem & 63;
#pragma unroll
        for (int nt = 0; nt < 4; ++nt) {
            int tok = nb + nt * 16 + low;
            u16 v = f2bf(acc[nt][r]);
            if (rem < 64)       QT [(head * N_TOK + tok) * 64 + c] = v;
            else if (rem < 128) KTm[(head * N_TOK + tok) * 64 + c] = v;
            else                Vc [(head * 64 + c) * N_TOK + tok] = v;
        }
    }
}

// ---------------- attention: waves-over-keys, K/V direct global->reg ----------
// Block: 64 queries, 4 waves; wave w handles key tiles {w, w+4, ..., w+60}.
// No barriers in main loop; P via wave-private swizzled LDS; in-block O combine.
struct Frags { bf16x8 ak[4][2]; bf16x8 bv[2][4]; };

__global__ __launch_bounds__(256, 1) void attn_kernel(const u16* __restrict__ QT,
                                                      const u16* __restrict__ KTm,
                                                      const u16* __restrict__ Vc,
                                                      u16* __restrict__ hT) {
    const int head = blockIdx.y;
    const int qb   = blockIdx.x * 64;
    const int tid  = threadIdx.x;
    const int wave = tid >> 6, lane = tid & 63;
    const int quad = lane >> 4, low = lane & 15;
    const int low7 = low & 7;

    const u16* Qh = QT  + head * N_TOK * 64;
    const u16* Kh = KTm + head * N_TOK * 64;
    const u16* Vh = Vc  + head * 64 * N_TOK;

    __shared__ union {
        u16 ps[4][4096];                                // 32KB: per-wave P 64x64, 16B-unit swizzle
        struct { float buf[2][64][65]; float lb[2][64]; } cb;  // 33.8KB combine
    } sm;
    u16* Pw = sm.ps[wave];

    bf16x8 ones;
#pragma unroll
    for (int i = 0; i < 8; ++i) ones[i] = (short)0x3F80;

    // Q B-frags (n=t, k=c), resident all kernel
    bf16x8 bq[4][2];
#pragma unroll
    for (int tn = 0; tn < 4; ++tn)
#pragma unroll
        for (int kh = 0; kh < 2; ++kh)
            bq[tn][kh] = *(const bf16x8*)(Qh + (qb + tn * 16 + low) * 64 + kh * 32 + quad * 8);

    f32x4 oa[4][4], lC[4];
#pragma unroll
    for (int tm = 0; tm < 4; ++tm) {
        lC[tm] = f32x4{0,0,0,0};
#pragma unroll
        for (int cn = 0; cn < 4; ++cn) oa[tm][cn] = f32x4{0,0,0,0};
    }

    auto load_frags = [&](Frags& F, int sbase) {
#pragma unroll
        for (int sq = 0; sq < 4; ++sq)
#pragma unroll
            for (int kh = 0; kh < 2; ++kh)
                F.ak[sq][kh] = *(const bf16x8*)(Kh + (sbase + sq * 16 + low) * 64 + kh * 32 + quad * 8);
#pragma unroll
        for (int f = 0; f < 2; ++f)
#pragma unroll
            for (int cn = 0; cn < 4; ++cn)
                F.bv[f][cn] = *(const bf16x8*)(Vh + (cn * 16 + low) * N_TOK + sbase + f * 32 + quad * 8);
    };

    auto compute_tile = [&](const Frags& F) {
        // S^T tiles: C[m=s][n=t]
        f32x4 sa[4][4];
#pragma unroll
        for (int sq = 0; sq < 4; ++sq)
#pragma unroll
            for (int tn = 0; tn < 4; ++tn) sa[sq][tn] = f32x4{0,0,0,0};
#pragma unroll
        for (int kh = 0; kh < 2; ++kh)
#pragma unroll
            for (int sq = 0; sq < 4; ++sq)
#pragma unroll
                for (int tn = 0; tn < 4; ++tn)
                    sa[sq][tn] = __builtin_amdgcn_mfma_f32_16x16x32_bf16(F.ak[sq][kh], bq[tn][kh], sa[sq][tn], 0, 0, 0);
        // P = exp2(S) (log2e folded into Wq), packed b64 stores, swizzled
#pragma unroll
        for (int sq = 0; sq < 4; ++sq)
#pragma unroll
            for (int tn = 0; tn < 4; ++tn) {
                float p0 = __builtin_amdgcn_exp2f(sa[sq][tn][0]);
                float p1 = __builtin_amdgcn_exp2f(sa[sq][tn][1]);
                float p2 = __builtin_amdgcn_exp2f(sa[sq][tn][2]);
                float p3 = __builtin_amdgcn_exp2f(sa[sq][tn][3]);
                uint2 pk; pk.x = packtr(p0, p1); pk.y = packtr(p2, p3);
                int u = (sq * 2 + (quad >> 1)) ^ low7;
                *(uint2*)(Pw + (tn * 16 + low) * 64 + u * 8 + (quad & 1) * 4) = pk;
            }
        asm volatile("s_waitcnt lgkmcnt(0)" ::: "memory");   // wave-private round-trip
        // O += P V^T, l += P*1
#pragma unroll
        for (int tm = 0; tm < 4; ++tm)
#pragma unroll
            for (int f = 0; f < 2; ++f) {
                bf16x8 ap = *(const bf16x8*)(Pw + (tm * 16 + low) * 64 + (((f * 4 + quad) ^ low7) * 8));
                lC[tm] = __builtin_amdgcn_mfma_f32_16x16x32_bf16(ap, ones, lC[tm], 0, 0, 0);
#pragma unroll
                for (int cn = 0; cn < 4; ++cn)
                    oa[tm][cn] = __builtin_amdgcn_mfma_f32_16x16x32_bf16(ap, F.bv[f][cn], oa[tm][cn], 0, 0, 0);
            }
    };

    Frags Fa, Fb;
    load_frags(Fa, wave * 64);
#pragma unroll 1
    for (int i = 0; i < 16; i += 2) {
        load_frags(Fb, (wave + 4 * (i + 1)) * 64);
        compute_tile(Fa);
        if (i + 2 < 16) load_frags(Fa, (wave + 4 * (i + 2)) * 64);
        compute_tile(Fb);
    }

    // ---- in-block combine across 4 waves (LDS reused from Ps) ----
    __syncthreads();
    if ((wave & 1) == 0) {
        int bsel = wave >> 1;
#pragma unroll
        for (int tm = 0; tm < 4; ++tm) {
#pragma unroll
            for (int r = 0; r < 4; ++r) {
                int t = tm * 16 + quad * 4 + r;
                if (low == 0) sm.cb.lb[bsel][t] = lC[tm][r];
#pragma unroll
                for (int cn = 0; cn < 4; ++cn)
                    sm.cb.buf[bsel][t][cn * 16 + low] = oa[tm][cn][r];
            }
        }
    }
    __syncthreads();
    if ((wave & 1) == 1) {
        int bsel = wave >> 1;
#pragma unroll
        for (int tm = 0; tm < 4; ++tm) {
#pragma unroll
            for (int r = 0; r < 4; ++r) {
                int t = tm * 16 + quad * 4 + r;
                if (low == 0) sm.cb.lb[bsel][t] += lC[tm][r];
#pragma unroll
                for (int cn = 0; cn < 4; ++cn)
                    sm.cb.buf[bsel][t][cn * 16 + low] += oa[tm][cn][r];
            }
        }
    }
    __syncthreads();
    {
        int t = tid >> 2, c0 = (tid & 3) * 16;
        float li = 1.f / (sm.cb.lb[0][t] + sm.cb.lb[1][t]);
#pragma unroll
        for (int j = 0; j < 16; ++j) {
            int c = c0 + j;
            float o = (sm.cb.buf[0][t][c] + sm.cb.buf[1][t][c]) * li;
            hT[(qb + t) * C_CH + head * 64 + c] = f2bf(o);
        }
    }
}

// ---------------- proj GEMM + bias + residual (fp32 out), 32-token tiles ----
__global__ __launch_bounds__(256) void proj_gemm(const u16* __restrict__ wp,
                                                 const u16* __restrict__ hT,
                                                 const float* __restrict__ bias,
                                                 const float* __restrict__ xres,
                                                 float* __restrict__ out) {
    const int nb = blockIdx.x * 32;
    const int mo = blockIdx.y * 64 + (threadIdx.x >> 6) * 16;
    const int lane = threadIdx.x & 63;
    const int quad = lane >> 4, low = lane & 15;

    f32x4 acc[2] = {f32x4{0,0,0,0}, f32x4{0,0,0,0}};
#pragma unroll
    for (int kc = 0; kc < 8; ++kc) {
        bf16x8 af = *(const bf16x8*)(wp + (mo + low) * 256 + kc * 32 + quad * 8);
#pragma unroll
        for (int nt = 0; nt < 2; ++nt) {
            bf16x8 bf_ = *(const bf16x8*)(hT + (nb + nt * 16 + low) * 256 + kc * 32 + quad * 8);
            acc[nt] = __builtin_amdgcn_mfma_f32_16x16x32_bf16(af, bf_, acc[nt], 0, 0, 0);
        }
    }
#pragma unroll
    for (int r = 0; r < 4; ++r) {
        int o = mo + quad * 4 + r;
        float bv = bias[o];
#pragma unroll
        for (int nt = 0; nt < 2; ++nt) {
            int tok = nb + nt * 16 + low;
            out[o * N_TOK + tok] = acc[nt][r] + bv + xres[o * N_TOK + tok];
        }
    }
}

extern "C" void kernel_launch(void* const* d_in, const int* in_sizes, int n_in,
                              void* d_out, int out_size, void* d_ws, size_t ws_size,
                              hipStream_t stream) {
    const float* x      = (const float*)d_in[0];
    const float* gamma  = (const float*)d_in[1];
    const float* beta   = (const float*)d_in[2];
    const float* w_qkv  = (const float*)d_in[3];
    const float* w_proj = (const float*)d_in[4];
    const float* b_proj = (const float*)d_in[5];
    float* out = (float*)d_out;

    char* base = (char*)d_ws;
    float2* part = (float2*)base;                      // 2 KB
    u16*    wq   = (u16*)(base + 4096);                // 384 KB
    u16*    wp   = (u16*)(base + 397312);              // 128 KB
    u16*    xt   = (u16*)(base + 528384);              // 2 MB
    u16*    QT   = (u16*)(base + 2625536);             // 2 MB
    u16*    KTm  = (u16*)(base + 4722688);             // 2 MB
    u16*    Vc   = (u16*)(base + 6819840);             // 2 MB
    u16*    hT   = (u16*)(base + 8916992);             // 2 MB

    prep      <<<1280, 256, 0, stream>>>(w_qkv, w_proj, x, wq, wp, part);
    norm_t    <<<dim3(64, 4),  256, 0, stream>>>(x, part, gamma, beta, xt);
    qkv_gemm  <<<dim3(64, 12), 256, 0, stream>>>(wq, xt, QT, KTm, Vc);
    attn_kernel<<<dim3(64, 4), 256, 0, stream>>>(QT, KTm, Vc, hT);
    proj_gemm <<<dim3(128, 4), 256, 0, stream>>>(wp, hT, b_proj, x, out);
}